// Round 7
// baseline (185.834 us; speedup 1.0000x reference)
//
#include <hip/hip_runtime.h>

typedef unsigned short u16;
typedef __bf16 bf16x8 __attribute__((ext_vector_type(8)));
typedef float f32x4 __attribute__((ext_vector_type(4)));

// Problem constants: B=16, C=256, H=W=32 -> N=1024, heads=4, Dh=64, groups=8
// scale = 1/sqrt(64) = 0.125; fold log2(e) so softmax uses exp2 (v_exp_f32).
#define QSCALE 0.18033688011112042f  // 0.125 * log2(e)

__device__ __forceinline__ u16 f2bf(float f) {
  __bf16 h = (__bf16)f;  // RNE
  union { __bf16 b; u16 u; } cv;
  cv.b = h;
  return cv.u;
}
__device__ __forceinline__ unsigned pack2(float a, float b) {
#if __has_builtin(__builtin_amdgcn_cvt_pk_bf16_f32)
  typedef __bf16 bf16x2 __attribute__((ext_vector_type(2)));
  bf16x2 p = __builtin_amdgcn_cvt_pk_bf16_f32(a, b);
  union { bf16x2 v; unsigned u; } cv;
  cv.v = p;
  return cv.u;
#else
  return (unsigned)f2bf(a) | ((unsigned)f2bf(b) << 16);
#endif
}
__device__ __forceinline__ float fexp2(float x) {
  return __builtin_amdgcn_exp2f(x);  // raw v_exp_f32; inputs well in-range
}

// ---------------------------------------------------------------------------
// prep: blocks 0..255 convert weights fp32->bf16; blocks 256..383 gn stats.
__global__ __launch_bounds__(256) void prep(
    const float* __restrict__ qw, const float* __restrict__ pw,
    const float* __restrict__ x,
    u16* __restrict__ qwb, u16* __restrict__ pwb, float* __restrict__ stats) {
  __shared__ float sh1[256], sh2[256];
  const int blk = blockIdx.x;
  const int t = threadIdx.x;
  if (blk < 256) {
    int i = blk * 256 + t;
    const float* s; u16* d; int j;
    if (i < 49152) { s = qw; d = qwb; j = i; }
    else           { s = pw; d = pwb; j = i - 49152; }
    float4 v = *(const float4*)(s + (size_t)j * 4);
    uint2 o; o.x = pack2(v.x, v.y); o.y = pack2(v.z, v.w);
    *(uint2*)(d + (size_t)j * 4) = o;
    return;
  }
  const int bid = blk - 256;  // b*8+g
  int cl = t >> 3;
  int off = (t & 7) * 4;
  const float* p = x + (size_t)bid * 32768 + (size_t)cl * 1024 + off;
  float s = 0.f, ss = 0.f;
#pragma unroll 8
  for (int i = 0; i < 32; ++i) {
    float4 v = *(const float4*)(p + i * 32);
    s += v.x + v.y + v.z + v.w;
    ss += v.x * v.x + v.y * v.y + v.z * v.z + v.w * v.w;
  }
  sh1[t] = s; sh2[t] = ss;
  __syncthreads();
  for (int st = 128; st > 0; st >>= 1) {
    if (t < st) { sh1[t] += sh1[t + st]; sh2[t] += sh2[t + st]; }
    __syncthreads();
  }
  if (t == 0) {
    float mean = sh1[0] * (1.f / 32768.f);
    float var = sh2[0] * (1.f / 32768.f) - mean * mean;
    stats[bid * 2] = mean;
    stats[bid * 2 + 1] = rsqrtf(var + 1e-5f);
  }
}

// ---------------------------------------------------------------------------
// QKV GEMM with FUSED GroupNorm: C[768 x 16384] = W[768 x 256] * xn^T where
// xn = GN(x) is computed on the fly. B-staging reads x fp32 [c][n], applies
// w*x+b (per-c affine folded with group stats), transposes to LDS bf16
// [n][c] with XOR-granule swizzle. Group g == k-step ki (BK=32 == ch/group).
// Grid 768 linear; decode clusters the 6 m-blocks of one n-tile on one XCD.
__global__ __launch_bounds__(256) void gemm_qkv(
    const u16* __restrict__ A, const float* __restrict__ x,
    const float* __restrict__ stats,
    const float* __restrict__ gw, const float* __restrict__ gb,
    const float* __restrict__ bias,
    u16* __restrict__ o_q, u16* __restrict__ o_k, u16* __restrict__ o_v) {
  const int l = blockIdx.x;        // 768
  const int xcd = l & 7;
  const int i2 = l >> 3;           // 0..95
  const int m_t = i2 % 6;
  const int nl6 = i2 / 6;          // 0..15
  const int nt = xcd * 16 + nl6;   // n-tile 0..127
  const int m0 = m_t * 128;
  const int n0 = nt * 128;
  const int b = nt >> 3;
  const int nsp0 = (nt & 7) * 128;

  const int t = threadIdx.x;
  const int wave = t >> 6, lane = t & 63, lm = lane & 15, quad = lane >> 4;
  const int wr = wave >> 1, wc = wave & 1;

  __shared__ u16 As[2][128 * 32];
  __shared__ u16 Bs[2][128 * 32];

  f32x4 acc[4][4];
  const f32x4 fzero = {0.f, 0.f, 0.f, 0.f};
#pragma unroll
  for (int i = 0; i < 4; ++i)
#pragma unroll
    for (int j = 0; j < 4; ++j) acc[i][j] = fzero;

  // A staging (weights, bf16 row-major [768][256])
  const int srow = t >> 2, scol = (t & 3) * 8;
  const u16* pA0 = A + (size_t)(m0 + srow) * 256 + scol;
  const u16* pA1 = A + (size_t)(m0 + 64 + srow) * 256 + scol;

  // B staging: thread owns n-pair 2*n2, 2*n2+1 and c-granule gq (wave-uniform)
  const int n2 = t & 63, gq = t >> 6;
  const float* xb = x + (size_t)b * 262144 + nsp0 + 2 * n2;
  const int gsw = (gq ^ (n2 & 3)) * 8;  // swizzled granule offset (u16)

  float2 vB[8];
  uint4 vA0, vA1;

#define LD_B(ki)                                                       \
  {                                                                    \
    const int cb = (ki) * 32 + gq * 8;                                 \
    _Pragma("unroll") for (int i = 0; i < 8; ++i)                      \
        vB[i] = *(const float2*)(xb + (size_t)(cb + i) * 1024);        \
  }
#define ST_B(ki, buf)                                                  \
  {                                                                    \
    const int cb = (ki) * 32 + gq * 8;                                 \
    const float mu = stats[(b * 8 + (ki)) * 2];                        \
    const float rq = stats[(b * 8 + (ki)) * 2 + 1];                    \
    float e0[8], e1[8];                                                \
    _Pragma("unroll") for (int i = 0; i < 8; ++i) {                    \
      const float w = gw[cb + i] * rq;                                 \
      const float bb = gb[cb + i] - mu * w;                            \
      e0[i] = vB[i].x * w + bb;                                        \
      e1[i] = vB[i].y * w + bb;                                        \
    }                                                                  \
    uint4 w0, w1;                                                      \
    w0.x = pack2(e0[0], e0[1]); w0.y = pack2(e0[2], e0[3]);            \
    w0.z = pack2(e0[4], e0[5]); w0.w = pack2(e0[6], e0[7]);            \
    w1.x = pack2(e1[0], e1[1]); w1.y = pack2(e1[2], e1[3]);            \
    w1.z = pack2(e1[4], e1[5]); w1.w = pack2(e1[6], e1[7]);            \
    *(uint4*)(Bs[buf] + (2 * n2) * 32 + gsw) = w0;                     \
    *(uint4*)(Bs[buf] + (2 * n2 + 1) * 32 + gsw) = w1;                 \
  }

  // k-step 0 staged, k-step 1 prefetched to regs
  LD_B(0);
  vA0 = *(const uint4*)pA0;
  vA1 = *(const uint4*)pA1;
  ST_B(0, 0);
  *(uint4*)(As[0] + srow * 32 + scol) = vA0;
  *(uint4*)(As[0] + (64 + srow) * 32 + scol) = vA1;
  LD_B(1);
  vA0 = *(const uint4*)(pA0 + 32);
  vA1 = *(const uint4*)(pA1 + 32);

  for (int ki = 0; ki < 8; ++ki) {
    __syncthreads();
    if (ki + 1 < 8) {
      ST_B(ki + 1, (ki + 1) & 1);
      u16* as = As[(ki + 1) & 1];
      *(uint4*)(as + srow * 32 + scol) = vA0;
      *(uint4*)(as + (64 + srow) * 32 + scol) = vA1;
    }
    if (ki + 2 < 8) {
      LD_B(ki + 2);
      vA0 = *(const uint4*)(pA0 + (ki + 2) * 32);
      vA1 = *(const uint4*)(pA1 + (ki + 2) * 32);
    }
    const u16* as = As[ki & 1];
    const u16* bs = Bs[ki & 1];
    bf16x8 af[4], bf[4];
#pragma unroll
    for (int mb = 0; mb < 4; ++mb)
      af[mb] = *(const bf16x8*)(as + (wr * 64 + mb * 16 + lm) * 32 + quad * 8);
#pragma unroll
    for (int nb = 0; nb < 4; ++nb) {
      const int row = wc * 64 + nb * 16 + lm;
      bf[nb] = *(const bf16x8*)(bs + row * 32 + ((quad ^ ((row >> 1) & 3)) * 8));
    }
#pragma unroll
    for (int mb = 0; mb < 4; ++mb)
#pragma unroll
      for (int nb = 0; nb < 4; ++nb)
        acc[mb][nb] = __builtin_amdgcn_mfma_f32_16x16x32_bf16(af[mb], bf[nb],
                                                              acc[mb][nb], 0, 0, 0);
  }
#undef LD_B
#undef ST_B

#pragma unroll
  for (int mb = 0; mb < 4; ++mb) {
#pragma unroll
    for (int nb = 0; nb < 4; ++nb) {
      const int o = m0 + wr * 64 + mb * 16 + 4 * quad;  // +r along m
      const int ng = n0 + wc * 64 + nb * 16 + lm;
      const int bb = ng >> 10, n = ng & 1023;
      const int kind = o >> 8;  // uniform per mb
      if (kind == 1) {  // k -> [bh][n][64d], pack 4 d per store
        ushort4 pk;
        pk.x = f2bf(acc[mb][nb][0] + bias[o]);
        pk.y = f2bf(acc[mb][nb][1] + bias[o + 1]);
        pk.z = f2bf(acc[mb][nb][2] + bias[o + 2]);
        pk.w = f2bf(acc[mb][nb][3] + bias[o + 3]);
        const int h = (o >> 6) & 3;
        *(ushort4*)(o_k + ((size_t)((bb * 4 + h) * 1024 + n)) * 64 + (o & 63)) = pk;
      } else {  // q / v -> [b][oc][n], lane-contiguous stores
        u16* dst = (kind == 0) ? o_q : o_v;
        const float sc = (kind == 0) ? QSCALE : 1.f;
        const int oc = o & 255;
#pragma unroll
        for (int r = 0; r < 4; ++r)
          dst[((size_t)(bb * 256 + oc + r)) * 1024 + n] =
              f2bf((acc[mb][nb][r] + bias[o + r]) * sc);
      }
    }
  }
}

// ---------------------------------------------------------------------------
// Proj NT bf16 GEMM, 64m x 128n tile (512 blocks -> multi-block residency).
// Epilogue: +bias +skip -> fp32 out.
__global__ __launch_bounds__(256) void gemm_proj(
    const u16* __restrict__ A, const u16* __restrict__ Bm,
    const float* __restrict__ bias,
    const float* __restrict__ skip, float* __restrict__ out) {
  const int m0 = blockIdx.y * 64;
  const int n0 = blockIdx.x * 128;
  const int t = threadIdx.x;
  const int wave = t >> 6, lane = t & 63, lm = lane & 15, quad = lane >> 4;
  const int wr = wave >> 1, wc = wave & 1;

  __shared__ u16 As[2][64 * 32];
  __shared__ u16 Bs[2][128 * 32];

  f32x4 acc[2][4];
  const f32x4 fzero = {0.f, 0.f, 0.f, 0.f};
#pragma unroll
  for (int i = 0; i < 2; ++i)
#pragma unroll
    for (int j = 0; j < 4; ++j) acc[i][j] = fzero;

  const int srow = t >> 2, scol = (t & 3) * 8;
  const u16* pA0 = A + (size_t)(m0 + srow) * 256 + scol;
  const u16* pB0 = Bm + (size_t)(n0 + srow) * 256 + scol;
  const u16* pB1 = Bm + (size_t)(n0 + 64 + srow) * 256 + scol;

  uint4 pa0 = *(const uint4*)pA0;
  uint4 pb0 = *(const uint4*)pB0;
  uint4 pb1 = *(const uint4*)pB1;
  *(uint4*)(As[0] + srow * 32 + scol) = pa0;
  *(uint4*)(Bs[0] + srow * 32 + scol) = pb0;
  *(uint4*)(Bs[0] + (64 + srow) * 32 + scol) = pb1;
  pa0 = *(const uint4*)(pA0 + 32);
  pb0 = *(const uint4*)(pB0 + 32);
  pb1 = *(const uint4*)(pB1 + 32);

  for (int ki = 0; ki < 8; ++ki) {
    __syncthreads();
    if (ki + 1 < 8) {
      u16* as = As[(ki + 1) & 1];
      u16* bs = Bs[(ki + 1) & 1];
      *(uint4*)(as + srow * 32 + scol) = pa0;
      *(uint4*)(bs + srow * 32 + scol) = pb0;
      *(uint4*)(bs + (64 + srow) * 32 + scol) = pb1;
    }
    if (ki + 2 < 8) {
      const int ko = (ki + 2) * 32;
      pa0 = *(const uint4*)(pA0 + ko);
      pb0 = *(const uint4*)(pB0 + ko);
      pb1 = *(const uint4*)(pB1 + ko);
    }
    const u16* as = As[ki & 1];
    const u16* bs = Bs[ki & 1];
    bf16x8 af[2], bf[4];
#pragma unroll
    for (int mb = 0; mb < 2; ++mb)
      af[mb] = *(const bf16x8*)(as + (wr * 32 + mb * 16 + lm) * 32 + quad * 8);
#pragma unroll
    for (int nb = 0; nb < 4; ++nb)
      bf[nb] = *(const bf16x8*)(bs + (wc * 64 + nb * 16 + lm) * 32 + quad * 8);
#pragma unroll
    for (int mb = 0; mb < 2; ++mb)
#pragma unroll
      for (int nb = 0; nb < 4; ++nb)
        acc[mb][nb] = __builtin_amdgcn_mfma_f32_16x16x32_bf16(af[mb], bf[nb],
                                                              acc[mb][nb], 0, 0, 0);
  }

#pragma unroll
  for (int mb = 0; mb < 2; ++mb) {
#pragma unroll
    for (int nb = 0; nb < 4; ++nb) {
      const int o = m0 + wr * 32 + mb * 16 + 4 * quad;
      const int ng = n0 + wc * 64 + nb * 16 + lm;
      const int b = ng >> 10, n = ng & 1023;
#pragma unroll
      for (int r = 0; r < 4; ++r) {
        const size_t oi = ((size_t)(b * 256 + o + r)) * 1024 + n;
        out[oi] = acc[mb][nb][r] + bias[o + r] + skip[oi];
      }
    }
  }
}

// ---------------------------------------------------------------------------
// Flash attention v7. Block = 128 threads = 2 waves x 32 q-rows (64 rows),
// grid 1024, LDS 40960 B -> 4 blocks/CU (same residency as v6) with v5's
// 2-i-block register blocking: each K/V frag read feeds TWO MFMAs, cutting
// per-CU LDS-pipe load ~33% (the v6 bottleneck). S^T trick (mfma(A=K,B=Q)) ->
// P j-contiguous per lane: b64 P-writes, scalar per-lane row-sum. No-max
// softmax via raw v_exp_f32. K/V dbuf, 1 barrier/chunk, register prefetch.
__global__ __launch_bounds__(128) void attn_fused(
    const u16* __restrict__ qdn, const u16* __restrict__ knd,
    const u16* __restrict__ vdn, u16* __restrict__ att) {
  const int bid = blockIdx.x;  // 1024
  const int bh = (bid & 7) * 8 + ((bid >> 3) & 7);  // 8 bh per XCD
  const int qtile = bid >> 6;                       // 0..15 (64 rows each)
  const int t = threadIdx.x;
  const int wave = t >> 6, lane = t & 63, lm = lane & 15, quad = lane >> 4;

  const u16* qb = qdn + (size_t)bh * 65536;
  const u16* kb = knd + (size_t)bh * 65536;
  const u16* vb = vdn + (size_t)bh * 65536;

  __shared__ u16 KV[2][2][64 * 64];  // 32768 B
  __shared__ u16 QP[64 * 64];        // 8192 B; Q^T then per-wave P slices

  // ---- staging: 8 x uint4 per thread (4 K + 4 V), XOR-oct swizzle ----
  int lk_[4];
  const u16 *kg_[4], *vg_[4];
#pragma unroll
  for (int i = 0; i < 4; ++i) {
    const int e = t + 128 * i;
    const int r = e >> 3, c = e & 7;
    lk_[i] = r * 64 + ((c ^ (r & 7)) * 8);
    kg_[i] = kb + r * 64 + c * 8;    // + jc*4096
    vg_[i] = vb + r * 1024 + c * 8;  // + jc*64
  }
  uint4 pk[4], pv[4];
#pragma unroll
  for (int i = 0; i < 4; ++i) {
    pk[i] = *(const uint4*)kg_[i];
    pv[i] = *(const uint4*)vg_[i];
  }

  // ---- Q transpose: global [d][n] -> QP[n-local][d] (swizzled), 64 rows ----
  {
    const int dbase = t >> 3, ngq = t & 7;
#pragma unroll
    for (int s = 0; s < 4; ++s) {
      const int d0 = dbase + 16 * s;
      union { uint4 v; u16 sv[8]; } tq;
      tq.v = *(const uint4*)(qb + (size_t)d0 * 1024 + qtile * 64 + ngq * 8);
      const int oa = d0 >> 3, dl = d0 & 7;
#pragma unroll
      for (int k = 0; k < 8; ++k) {
        const int row = ngq * 8 + k;  // row & 7 == k
        QP[row * 64 + ((oa ^ k) * 8) + dl] = tq.sv[k];
      }
    }
  }

  // stage chunk 0 into buf0, prefetch chunk 1
#pragma unroll
  for (int i = 0; i < 4; ++i) {
    *(uint4*)(KV[0][0] + lk_[i]) = pk[i];
    *(uint4*)(KV[0][1] + lk_[i]) = pv[i];
  }
#pragma unroll
  for (int i = 0; i < 4; ++i) {
    pk[i] = *(const uint4*)(kg_[i] + 4096);
    pv[i] = *(const uint4*)(vg_[i] + 64);
  }
  __syncthreads();

  const int swz0 = (quad ^ (lm & 7)) * 8;
  const int swz1 = ((4 + quad) ^ (lm & 7)) * 8;

  // q-frags for this wave's two i-blocks (rows wave*32 + ib*16 + lm)
  bf16x8 qf[2][2];
  u16* Prow[2];
#pragma unroll
  for (int ib = 0; ib < 2; ++ib) {
    u16* rp = QP + (wave * 32 + ib * 16 + lm) * 64;
    qf[ib][0] = *(const bf16x8*)(rp + swz0);
    qf[ib][1] = *(const bf16x8*)(rp + swz1);
    Prow[ib] = rp;  // reused as this wave's private P slice
  }

  const f32x4 fzero = {0.f, 0.f, 0.f, 0.f};
  f32x4 oacc[2][4];
#pragma unroll
  for (int ib = 0; ib < 2; ++ib)
#pragma unroll
    for (int d = 0; d < 4; ++d) oacc[ib][d] = fzero;
  float lp[2] = {0.f, 0.f};

  for (int jc = 0; jc < 16; ++jc) {
    if (jc) __syncthreads();
    if (jc + 1 < 16) {
      u16* kd = KV[(jc + 1) & 1][0];
      u16* vd = KV[(jc + 1) & 1][1];
#pragma unroll
      for (int i = 0; i < 4; ++i) {
        *(uint4*)(kd + lk_[i]) = pk[i];
        *(uint4*)(vd + lk_[i]) = pv[i];
      }
    }
    if (jc + 2 < 16) {
#pragma unroll
      for (int i = 0; i < 4; ++i) {
        pk[i] = *(const uint4*)(kg_[i] + (jc + 2) * 4096);
        pv[i] = *(const uint4*)(vg_[i] + (jc + 2) * 64);
      }
    }
    const u16* Ks = KV[jc & 1][0];
    const u16* Vs = KV[jc & 1][1];

    f32x4 sacc[2][4];
#pragma unroll
    for (int ib = 0; ib < 2; ++ib)
#pragma unroll
      for (int jb = 0; jb < 4; ++jb) sacc[ib][jb] = fzero;
#pragma unroll
    for (int jb = 0; jb < 4; ++jb) {
      const int row = (jb * 16 + lm) * 64;
      bf16x8 kf0 = *(const bf16x8*)(Ks + row + swz0);
      bf16x8 kf1 = *(const bf16x8*)(Ks + row + swz1);
      sacc[0][jb] = __builtin_amdgcn_mfma_f32_16x16x32_bf16(kf0, qf[0][0], sacc[0][jb], 0, 0, 0);
      sacc[0][jb] = __builtin_amdgcn_mfma_f32_16x16x32_bf16(kf1, qf[0][1], sacc[0][jb], 0, 0, 0);
      sacc[1][jb] = __builtin_amdgcn_mfma_f32_16x16x32_bf16(kf0, qf[1][0], sacc[1][jb], 0, 0, 0);
      sacc[1][jb] = __builtin_amdgcn_mfma_f32_16x16x32_bf16(kf1, qf[1][1], sacc[1][jb], 0, 0, 0);
    }
    // P: row i (= lane's lm within i-block), 4 j-contiguous values -> b64
#pragma unroll
    for (int ib = 0; ib < 2; ++ib) {
#pragma unroll
      for (int jb = 0; jb < 4; ++jb) {
        const float e0 = fexp2(sacc[ib][jb][0]);
        const float e1 = fexp2(sacc[ib][jb][1]);
        const float e2 = fexp2(sacc[ib][jb][2]);
        const float e3 = fexp2(sacc[ib][jb][3]);
        lp[ib] += (e0 + e1) + (e2 + e3);
        uint2 pw;
        pw.x = pack2(e0, e1);
        pw.y = pack2(e2, e3);
        const int oct = 2 * jb + (quad >> 1);
        *(uint2*)(Prow[ib] + ((oct ^ (lm & 7)) * 8) + 4 * (quad & 1)) = pw;
      }
    }
    bf16x8 pf[2][2];
#pragma unroll
    for (int ib = 0; ib < 2; ++ib) {
      pf[ib][0] = *(const bf16x8*)(Prow[ib] + swz0);
      pf[ib][1] = *(const bf16x8*)(Prow[ib] + swz1);
    }
#pragma unroll
    for (int db = 0; db < 4; ++db) {
      const int row = (db * 16 + lm) * 64;
      bf16x8 vf0 = *(const bf16x8*)(Vs + row + swz0);
      bf16x8 vf1 = *(const bf16x8*)(Vs + row + swz1);
      oacc[0][db] = __builtin_amdgcn_mfma_f32_16x16x32_bf16(pf[0][0], vf0, oacc[0][db], 0, 0, 0);
      oacc[0][db] = __builtin_amdgcn_mfma_f32_16x16x32_bf16(pf[0][1], vf1, oacc[0][db], 0, 0, 0);
      oacc[1][db] = __builtin_amdgcn_mfma_f32_16x16x32_bf16(pf[1][0], vf0, oacc[1][db], 0, 0, 0);
      oacc[1][db] = __builtin_amdgcn_mfma_f32_16x16x32_bf16(pf[1][1], vf1, oacc[1][db], 0, 0, 0);
    }
  }

  // epilogue: full row-sums via 2 shuffles, normalize, store.
  const int b = bh >> 2, h = bh & 3;
#pragma unroll
  for (int ib = 0; ib < 2; ++ib) {
    float rs = lp[ib];
    rs += __shfl_xor(rs, 16);
    rs += __shfl_xor(rs, 32);
#pragma unroll
    for (int r = 0; r < 4; ++r) {
      const float inv = 1.f / __shfl(rs, 4 * quad + r);
      const int n = qtile * 64 + wave * 32 + ib * 16 + 4 * quad + r;
#pragma unroll
      for (int db = 0; db < 4; ++db) {
        const int c = h * 64 + db * 16 + lm;
        att[((size_t)(b * 1024 + n)) * 256 + c] = f2bf(oacc[ib][db][r] * inv);
      }
    }
  }
}

// ---------------------------------------------------------------------------
extern "C" void kernel_launch(void* const* d_in, const int* in_sizes, int n_in,
                              void* d_out, int out_size, void* d_ws, size_t ws_size,
                              hipStream_t stream) {
  const float* x      = (const float*)d_in[0];
  const float* gn_w   = (const float*)d_in[1];
  const float* gn_b   = (const float*)d_in[2];
  const float* qkv_w  = (const float*)d_in[3];
  const float* qkv_b  = (const float*)d_in[4];
  const float* proj_w = (const float*)d_in[5];
  const float* proj_b = (const float*)d_in[6];
  float* out = (float*)d_out;

  char* ws = (char*)d_ws;
  float* stats = (float*)(ws + 0);            // 128*2 fp32
  u16* qwb = (u16*)(ws + 4096);               // 768*256 bf16
  u16* pwb = (u16*)(ws + 397312);             // 256*256 bf16
  u16* qdn = (u16*)(ws + 8916992);            // [64bh][64d][1024n] bf16
  u16* knd = (u16*)(ws + 17305600);           // [64bh][1024n][64d] bf16
  u16* vdn = (u16*)(ws + 25694208);           // [64bh][64d][1024n] bf16
  u16* att = (u16*)(ws + 34082816);           // [16][1024][256] bf16

  prep<<<384, 256, 0, stream>>>(qkv_w, proj_w, x, qwb, pwb, stats);
  gemm_qkv<<<768, 256, 0, stream>>>(qwb, x, stats, gn_w, gn_b, qkv_b,
                                    qdn, knd, vdn);
  attn_fused<<<1024, 128, 0, stream>>>(qdn, knd, vdn, att);
  gemm_proj<<<dim3(128, 4), 256, 0, stream>>>(pwb, att, proj_b, x, out);
}

// Round 8
// 139.978 us; speedup vs baseline: 1.3276x; 1.3276x over previous
//
#include <hip/hip_runtime.h>

typedef unsigned short u16;
typedef __bf16 bf16x8 __attribute__((ext_vector_type(8)));
typedef float f32x4 __attribute__((ext_vector_type(4)));

// Problem constants: B=16, C=256, H=W=32 -> N=1024, heads=4, Dh=64, groups=8
// scale = 1/sqrt(64) = 0.125; fold log2(e) so softmax uses exp2 (v_exp_f32).
#define QSCALE 0.18033688011112042f  // 0.125 * log2(e)

__device__ __forceinline__ u16 f2bf(float f) {
  __bf16 h = (__bf16)f;  // RNE
  union { __bf16 b; u16 u; } cv;
  cv.b = h;
  return cv.u;
}
__device__ __forceinline__ unsigned pack2(float a, float b) {
#if __has_builtin(__builtin_amdgcn_cvt_pk_bf16_f32)
  typedef __bf16 bf16x2 __attribute__((ext_vector_type(2)));
  bf16x2 p = __builtin_amdgcn_cvt_pk_bf16_f32(a, b);
  union { bf16x2 v; unsigned u; } cv;
  cv.v = p;
  return cv.u;
#else
  return (unsigned)f2bf(a) | ((unsigned)f2bf(b) << 16);
#endif
}
__device__ __forceinline__ float fexp2(float x) {
  return __builtin_amdgcn_exp2f(x);  // raw v_exp_f32; inputs well in-range
}

// ---------------------------------------------------------------------------
// prep: blocks 0..255 convert weights fp32->bf16; blocks 256..383 gn stats.
__global__ __launch_bounds__(256) void prep(
    const float* __restrict__ qw, const float* __restrict__ pw,
    const float* __restrict__ x,
    u16* __restrict__ qwb, u16* __restrict__ pwb, float* __restrict__ stats) {
  __shared__ float sh1[256], sh2[256];
  const int blk = blockIdx.x;
  const int t = threadIdx.x;
  if (blk < 256) {
    int i = blk * 256 + t;
    const float* s; u16* d; int j;
    if (i < 49152) { s = qw; d = qwb; j = i; }
    else           { s = pw; d = pwb; j = i - 49152; }
    float4 v = *(const float4*)(s + (size_t)j * 4);
    uint2 o; o.x = pack2(v.x, v.y); o.y = pack2(v.z, v.w);
    *(uint2*)(d + (size_t)j * 4) = o;
    return;
  }
  const int bid = blk - 256;  // b*8+g
  int cl = t >> 3;
  int off = (t & 7) * 4;
  const float* p = x + (size_t)bid * 32768 + (size_t)cl * 1024 + off;
  float s = 0.f, ss = 0.f;
#pragma unroll 8
  for (int i = 0; i < 32; ++i) {
    float4 v = *(const float4*)(p + i * 32);
    s += v.x + v.y + v.z + v.w;
    ss += v.x * v.x + v.y * v.y + v.z * v.z + v.w * v.w;
  }
  sh1[t] = s; sh2[t] = ss;
  __syncthreads();
  for (int st = 128; st > 0; st >>= 1) {
    if (t < st) { sh1[t] += sh1[t + st]; sh2[t] += sh2[t + st]; }
    __syncthreads();
  }
  if (t == 0) {
    float mean = sh1[0] * (1.f / 32768.f);
    float var = sh2[0] * (1.f / 32768.f) - mean * mean;
    stats[bid * 2] = mean;
    stats[bid * 2 + 1] = rsqrtf(var + 1e-5f);
  }
}

// ---------------------------------------------------------------------------
// QKV GEMM with FUSED GroupNorm: C[768 x 16384] = W[768 x 256] * xn^T where
// xn = GN(x) is computed on the fly. B-staging reads x fp32 [c][n], applies
// w*x+b (per-c affine folded with group stats), transposes to LDS bf16
// [n][c] with XOR-granule swizzle. Group g == k-step ki (BK=32 == ch/group).
// Grid 768 linear; decode clusters the 6 m-blocks of one n-tile on one XCD.
__global__ __launch_bounds__(256) void gemm_qkv(
    const u16* __restrict__ A, const float* __restrict__ x,
    const float* __restrict__ stats,
    const float* __restrict__ gw, const float* __restrict__ gb,
    const float* __restrict__ bias,
    u16* __restrict__ o_q, u16* __restrict__ o_k, u16* __restrict__ o_v) {
  const int l = blockIdx.x;        // 768
  const int xcd = l & 7;
  const int i2 = l >> 3;           // 0..95
  const int m_t = i2 % 6;
  const int nl6 = i2 / 6;          // 0..15
  const int nt = xcd * 16 + nl6;   // n-tile 0..127
  const int m0 = m_t * 128;
  const int n0 = nt * 128;
  const int b = nt >> 3;
  const int nsp0 = (nt & 7) * 128;

  const int t = threadIdx.x;
  const int wave = t >> 6, lane = t & 63, lm = lane & 15, quad = lane >> 4;
  const int wr = wave >> 1, wc = wave & 1;

  __shared__ u16 As[2][128 * 32];
  __shared__ u16 Bs[2][128 * 32];

  f32x4 acc[4][4];
  const f32x4 fzero = {0.f, 0.f, 0.f, 0.f};
#pragma unroll
  for (int i = 0; i < 4; ++i)
#pragma unroll
    for (int j = 0; j < 4; ++j) acc[i][j] = fzero;

  // A staging (weights, bf16 row-major [768][256])
  const int srow = t >> 2, scol = (t & 3) * 8;
  const u16* pA0 = A + (size_t)(m0 + srow) * 256 + scol;
  const u16* pA1 = A + (size_t)(m0 + 64 + srow) * 256 + scol;

  // B staging: thread owns n-pair 2*n2, 2*n2+1 and c-granule gq (wave-uniform)
  const int n2 = t & 63, gq = t >> 6;
  const float* xb = x + (size_t)b * 262144 + nsp0 + 2 * n2;
  const int gsw = (gq ^ (n2 & 3)) * 8;  // swizzled granule offset (u16)

  float2 vB[8];
  uint4 vA0, vA1;

#define LD_B(ki)                                                       \
  {                                                                    \
    const int cb = (ki) * 32 + gq * 8;                                 \
    _Pragma("unroll") for (int i = 0; i < 8; ++i)                      \
        vB[i] = *(const float2*)(xb + (size_t)(cb + i) * 1024);        \
  }
#define ST_B(ki, buf)                                                  \
  {                                                                    \
    const int cb = (ki) * 32 + gq * 8;                                 \
    const float mu = stats[(b * 8 + (ki)) * 2];                        \
    const float rq = stats[(b * 8 + (ki)) * 2 + 1];                    \
    float e0[8], e1[8];                                                \
    _Pragma("unroll") for (int i = 0; i < 8; ++i) {                    \
      const float w = gw[cb + i] * rq;                                 \
      const float bb = gb[cb + i] - mu * w;                            \
      e0[i] = vB[i].x * w + bb;                                        \
      e1[i] = vB[i].y * w + bb;                                        \
    }                                                                  \
    uint4 w0, w1;                                                      \
    w0.x = pack2(e0[0], e0[1]); w0.y = pack2(e0[2], e0[3]);            \
    w0.z = pack2(e0[4], e0[5]); w0.w = pack2(e0[6], e0[7]);            \
    w1.x = pack2(e1[0], e1[1]); w1.y = pack2(e1[2], e1[3]);            \
    w1.z = pack2(e1[4], e1[5]); w1.w = pack2(e1[6], e1[7]);            \
    *(uint4*)(Bs[buf] + (2 * n2) * 32 + gsw) = w0;                     \
    *(uint4*)(Bs[buf] + (2 * n2 + 1) * 32 + gsw) = w1;                 \
  }

  // k-step 0 staged, k-step 1 prefetched to regs
  LD_B(0);
  vA0 = *(const uint4*)pA0;
  vA1 = *(const uint4*)pA1;
  ST_B(0, 0);
  *(uint4*)(As[0] + srow * 32 + scol) = vA0;
  *(uint4*)(As[0] + (64 + srow) * 32 + scol) = vA1;
  LD_B(1);
  vA0 = *(const uint4*)(pA0 + 32);
  vA1 = *(const uint4*)(pA1 + 32);

  for (int ki = 0; ki < 8; ++ki) {
    __syncthreads();
    if (ki + 1 < 8) {
      ST_B(ki + 1, (ki + 1) & 1);
      u16* as = As[(ki + 1) & 1];
      *(uint4*)(as + srow * 32 + scol) = vA0;
      *(uint4*)(as + (64 + srow) * 32 + scol) = vA1;
    }
    if (ki + 2 < 8) {
      LD_B(ki + 2);
      vA0 = *(const uint4*)(pA0 + (ki + 2) * 32);
      vA1 = *(const uint4*)(pA1 + (ki + 2) * 32);
    }
    const u16* as = As[ki & 1];
    const u16* bs = Bs[ki & 1];
    bf16x8 af[4], bf[4];
#pragma unroll
    for (int mb = 0; mb < 4; ++mb)
      af[mb] = *(const bf16x8*)(as + (wr * 64 + mb * 16 + lm) * 32 + quad * 8);
#pragma unroll
    for (int nb = 0; nb < 4; ++nb) {
      const int row = wc * 64 + nb * 16 + lm;
      bf[nb] = *(const bf16x8*)(bs + row * 32 + ((quad ^ ((row >> 1) & 3)) * 8));
    }
#pragma unroll
    for (int mb = 0; mb < 4; ++mb)
#pragma unroll
      for (int nb = 0; nb < 4; ++nb)
        acc[mb][nb] = __builtin_amdgcn_mfma_f32_16x16x32_bf16(af[mb], bf[nb],
                                                              acc[mb][nb], 0, 0, 0);
  }
#undef LD_B
#undef ST_B

#pragma unroll
  for (int mb = 0; mb < 4; ++mb) {
#pragma unroll
    for (int nb = 0; nb < 4; ++nb) {
      const int o = m0 + wr * 64 + mb * 16 + 4 * quad;  // +r along m
      const int ng = n0 + wc * 64 + nb * 16 + lm;
      const int bb = ng >> 10, n = ng & 1023;
      const int kind = o >> 8;  // uniform per mb
      if (kind == 1) {  // k -> [bh][n][64d], pack 4 d per store
        ushort4 pk;
        pk.x = f2bf(acc[mb][nb][0] + bias[o]);
        pk.y = f2bf(acc[mb][nb][1] + bias[o + 1]);
        pk.z = f2bf(acc[mb][nb][2] + bias[o + 2]);
        pk.w = f2bf(acc[mb][nb][3] + bias[o + 3]);
        const int h = (o >> 6) & 3;
        *(ushort4*)(o_k + ((size_t)((bb * 4 + h) * 1024 + n)) * 64 + (o & 63)) = pk;
      } else {  // q / v -> [b][oc][n], lane-contiguous stores
        u16* dst = (kind == 0) ? o_q : o_v;
        const float sc = (kind == 0) ? QSCALE : 1.f;
        const int oc = o & 255;
#pragma unroll
        for (int r = 0; r < 4; ++r)
          dst[((size_t)(bb * 256 + oc + r)) * 1024 + n] =
              f2bf((acc[mb][nb][r] + bias[o + r]) * sc);
      }
    }
  }
}

// ---------------------------------------------------------------------------
// Proj NT bf16 GEMM, 64m x 128n tile (512 blocks -> multi-block residency).
// Epilogue: +bias +skip -> fp32 out.
__global__ __launch_bounds__(256) void gemm_proj(
    const u16* __restrict__ A, const u16* __restrict__ Bm,
    const float* __restrict__ bias,
    const float* __restrict__ skip, float* __restrict__ out) {
  const int m0 = blockIdx.y * 64;
  const int n0 = blockIdx.x * 128;
  const int t = threadIdx.x;
  const int wave = t >> 6, lane = t & 63, lm = lane & 15, quad = lane >> 4;
  const int wr = wave >> 1, wc = wave & 1;

  __shared__ u16 As[2][64 * 32];
  __shared__ u16 Bs[2][128 * 32];

  f32x4 acc[2][4];
  const f32x4 fzero = {0.f, 0.f, 0.f, 0.f};
#pragma unroll
  for (int i = 0; i < 2; ++i)
#pragma unroll
    for (int j = 0; j < 4; ++j) acc[i][j] = fzero;

  const int srow = t >> 2, scol = (t & 3) * 8;
  const u16* pA0 = A + (size_t)(m0 + srow) * 256 + scol;
  const u16* pB0 = Bm + (size_t)(n0 + srow) * 256 + scol;
  const u16* pB1 = Bm + (size_t)(n0 + 64 + srow) * 256 + scol;

  uint4 pa0 = *(const uint4*)pA0;
  uint4 pb0 = *(const uint4*)pB0;
  uint4 pb1 = *(const uint4*)pB1;
  *(uint4*)(As[0] + srow * 32 + scol) = pa0;
  *(uint4*)(Bs[0] + srow * 32 + scol) = pb0;
  *(uint4*)(Bs[0] + (64 + srow) * 32 + scol) = pb1;
  pa0 = *(const uint4*)(pA0 + 32);
  pb0 = *(const uint4*)(pB0 + 32);
  pb1 = *(const uint4*)(pB1 + 32);

  for (int ki = 0; ki < 8; ++ki) {
    __syncthreads();
    if (ki + 1 < 8) {
      u16* as = As[(ki + 1) & 1];
      u16* bs = Bs[(ki + 1) & 1];
      *(uint4*)(as + srow * 32 + scol) = pa0;
      *(uint4*)(bs + srow * 32 + scol) = pb0;
      *(uint4*)(bs + (64 + srow) * 32 + scol) = pb1;
    }
    if (ki + 2 < 8) {
      const int ko = (ki + 2) * 32;
      pa0 = *(const uint4*)(pA0 + ko);
      pb0 = *(const uint4*)(pB0 + ko);
      pb1 = *(const uint4*)(pB1 + ko);
    }
    const u16* as = As[ki & 1];
    const u16* bs = Bs[ki & 1];
    bf16x8 af[2], bf[4];
#pragma unroll
    for (int mb = 0; mb < 2; ++mb)
      af[mb] = *(const bf16x8*)(as + (wr * 32 + mb * 16 + lm) * 32 + quad * 8);
#pragma unroll
    for (int nb = 0; nb < 4; ++nb)
      bf[nb] = *(const bf16x8*)(bs + (wc * 64 + nb * 16 + lm) * 32 + quad * 8);
#pragma unroll
    for (int mb = 0; mb < 2; ++mb)
#pragma unroll
      for (int nb = 0; nb < 4; ++nb)
        acc[mb][nb] = __builtin_amdgcn_mfma_f32_16x16x32_bf16(af[mb], bf[nb],
                                                              acc[mb][nb], 0, 0, 0);
  }

#pragma unroll
  for (int mb = 0; mb < 2; ++mb) {
#pragma unroll
    for (int nb = 0; nb < 4; ++nb) {
      const int o = m0 + wr * 32 + mb * 16 + 4 * quad;
      const int ng = n0 + wc * 64 + nb * 16 + lm;
      const int b = ng >> 10, n = ng & 1023;
#pragma unroll
      for (int r = 0; r < 4; ++r) {
        const size_t oi = ((size_t)(b * 256 + o + r)) * 1024 + n;
        out[oi] = acc[mb][nb][r] + bias[o + r] + skip[oi];
      }
    }
  }
}

// ---------------------------------------------------------------------------
// Flash attention v8 = v6 shape (proven: 256 threads, 16 rows/wave, grid 1024,
// LDS 40960 B -> 4 blocks/CU, VGPR ~60, NO spills) + raw v_exp_f32 and packed
// bf16 cvt (v7's micro-wins). S^T trick (mfma(A=K,B=Q)): P j-contiguous per
// lane -> 4x b64 P-writes, scalar per-lane row-sum (shuffles only in
// epilogue). K/V dbuf, 1 barrier/chunk, register prefetch, XCD swizzle.
// NOTE (r7 post-mortem): 128-thread/2-i-block variant spills (WRITE_SIZE
// 150 MB scratch) — per-thread staging doubles with half-size blocks.
__global__ __launch_bounds__(256) void attn_fused(
    const u16* __restrict__ qdn, const u16* __restrict__ knd,
    const u16* __restrict__ vdn, u16* __restrict__ att) {
  const int bid = blockIdx.x;  // 1024
  const int bh = (bid & 7) * 8 + ((bid >> 3) & 7);  // 8 bh per XCD
  const int qtile = bid >> 6;                       // 0..15
  const int t = threadIdx.x;
  const int wave = t >> 6, lane = t & 63, lm = lane & 15, quad = lane >> 4;

  const u16* qb = qdn + (size_t)bh * 65536;
  const u16* kb = knd + (size_t)bh * 65536;
  const u16* vb = vdn + (size_t)bh * 65536;

  __shared__ u16 KV[2][2][64 * 64];  // 32768 B
  __shared__ u16 QP[64 * 64];        // 8192 B; Q^T then per-wave P slices

  // ---- staging addresses (16B units, XOR-oct swizzle) ----
  const int e1 = t + 256;
  const int r0 = t >> 3, c0_ = t & 7, r1 = e1 >> 3, c1_ = e1 & 7;
  const int lk0 = r0 * 64 + ((c0_ ^ (r0 & 7)) * 8);
  const int lk1 = r1 * 64 + ((c1_ ^ (r1 & 7)) * 8);
  const u16* kg0 = kb + r0 * 64 + c0_ * 8;    // + jc*4096
  const u16* kg1 = kb + r1 * 64 + c1_ * 8;
  const u16* vg0 = vb + r0 * 1024 + c0_ * 8;  // + jc*64
  const u16* vg1 = vb + r1 * 1024 + c1_ * 8;

  uint4 pk0 = *(const uint4*)kg0;
  uint4 pk1 = *(const uint4*)kg1;
  uint4 pv0 = *(const uint4*)vg0;
  uint4 pv1 = *(const uint4*)vg1;

  // ---- Q transpose: global [d][n] -> QP[n-local][d] (swizzled) ----
  {
    union { uint4 v; u16 s[8]; } tq0, tq1;
    const int d0 = t >> 3, ngq = t & 7;
    tq0.v = *(const uint4*)(qb + (size_t)d0 * 1024 + qtile * 64 + ngq * 8);
    tq1.v = *(const uint4*)(qb + (size_t)(32 + d0) * 1024 + qtile * 64 + ngq * 8);
    const int oa = d0 >> 3, ob = 4 + oa, dl = d0 & 7;
#pragma unroll
    for (int k = 0; k < 8; ++k) {
      const int row = ngq * 8 + k;  // row & 7 == k
      QP[row * 64 + ((oa ^ k) * 8) + dl] = tq0.s[k];
      QP[row * 64 + ((ob ^ k) * 8) + dl] = tq1.s[k];
    }
  }

  // stage chunk 0 into buf0, prefetch chunk 1
  *(uint4*)(KV[0][0] + lk0) = pk0;
  *(uint4*)(KV[0][0] + lk1) = pk1;
  *(uint4*)(KV[0][1] + lk0) = pv0;
  *(uint4*)(KV[0][1] + lk1) = pv1;
  pk0 = *(const uint4*)(kg0 + 4096);
  pk1 = *(const uint4*)(kg1 + 4096);
  pv0 = *(const uint4*)(vg0 + 64);
  pv1 = *(const uint4*)(vg1 + 64);
  __syncthreads();

  const int swz0 = (quad ^ (lm & 7)) * 8;
  const int swz1 = ((4 + quad) ^ (lm & 7)) * 8;
  u16* Pw = QP + (wave * 16 + lm) * 64;
  const bf16x8 qf0 = *(const bf16x8*)(Pw + swz0);
  const bf16x8 qf1 = *(const bf16x8*)(Pw + swz1);

  const f32x4 fzero = {0.f, 0.f, 0.f, 0.f};
  f32x4 oacc[4];
#pragma unroll
  for (int d = 0; d < 4; ++d) oacc[d] = fzero;
  float lp = 0.f;

  for (int jc = 0; jc < 16; ++jc) {
    if (jc) __syncthreads();
    if (jc + 1 < 16) {
      u16* kd = KV[(jc + 1) & 1][0];
      u16* vd = KV[(jc + 1) & 1][1];
      *(uint4*)(kd + lk0) = pk0;
      *(uint4*)(kd + lk1) = pk1;
      *(uint4*)(vd + lk0) = pv0;
      *(uint4*)(vd + lk1) = pv1;
    }
    if (jc + 2 < 16) {
      pk0 = *(const uint4*)(kg0 + (jc + 2) * 4096);
      pk1 = *(const uint4*)(kg1 + (jc + 2) * 4096);
      pv0 = *(const uint4*)(vg0 + (jc + 2) * 64);
      pv1 = *(const uint4*)(vg1 + (jc + 2) * 64);
    }
    const u16* Ks = KV[jc & 1][0];
    const u16* Vs = KV[jc & 1][1];

    f32x4 sacc[4];
#pragma unroll
    for (int jb = 0; jb < 4; ++jb) sacc[jb] = fzero;
#pragma unroll
    for (int jb = 0; jb < 4; ++jb) {
      const int row = (jb * 16 + lm) * 64;
      bf16x8 kf0 = *(const bf16x8*)(Ks + row + swz0);
      bf16x8 kf1 = *(const bf16x8*)(Ks + row + swz1);
      sacc[jb] = __builtin_amdgcn_mfma_f32_16x16x32_bf16(kf0, qf0, sacc[jb], 0, 0, 0);
      sacc[jb] = __builtin_amdgcn_mfma_f32_16x16x32_bf16(kf1, qf1, sacc[jb], 0, 0, 0);
    }
    // P: row i=lm, 4 j-contiguous values per (jb,quad) -> b64 writes
#pragma unroll
    for (int jb = 0; jb < 4; ++jb) {
      const float e0 = fexp2(sacc[jb][0]);
      const float e1_ = fexp2(sacc[jb][1]);
      const float e2 = fexp2(sacc[jb][2]);
      const float e3 = fexp2(sacc[jb][3]);
      lp += (e0 + e1_) + (e2 + e3);
      uint2 pw;
      pw.x = pack2(e0, e1_);
      pw.y = pack2(e2, e3);
      const int oct = 2 * jb + (quad >> 1);
      *(uint2*)(Pw + ((oct ^ (lm & 7)) * 8) + 4 * (quad & 1)) = pw;
    }
    bf16x8 pf0 = *(const bf16x8*)(Pw + swz0);
    bf16x8 pf1 = *(const bf16x8*)(Pw + swz1);
#pragma unroll
    for (int db = 0; db < 4; ++db) {
      const int row = (db * 16 + lm) * 64;
      bf16x8 vf0 = *(const bf16x8*)(Vs + row + swz0);
      bf16x8 vf1 = *(const bf16x8*)(Vs + row + swz1);
      oacc[db] = __builtin_amdgcn_mfma_f32_16x16x32_bf16(pf0, vf0, oacc[db], 0, 0, 0);
      oacc[db] = __builtin_amdgcn_mfma_f32_16x16x32_bf16(pf1, vf1, oacc[db], 0, 0, 0);
    }
  }

  // epilogue: full row-sums via 2 shuffles, normalize, store.
  float rs = lp;
  rs += __shfl_xor(rs, 16);
  rs += __shfl_xor(rs, 32);
  const int b = bh >> 2, h = bh & 3;
#pragma unroll
  for (int r = 0; r < 4; ++r) {
    const float inv = 1.f / __shfl(rs, 4 * quad + r);
    const int n = qtile * 64 + wave * 16 + 4 * quad + r;
#pragma unroll
    for (int db = 0; db < 4; ++db) {
      const int c = h * 64 + db * 16 + lm;
      att[((size_t)(b * 1024 + n)) * 256 + c] = f2bf(oacc[db][r] * inv);
    }
  }
}

// ---------------------------------------------------------------------------
extern "C" void kernel_launch(void* const* d_in, const int* in_sizes, int n_in,
                              void* d_out, int out_size, void* d_ws, size_t ws_size,
                              hipStream_t stream) {
  const float* x      = (const float*)d_in[0];
  const float* gn_w   = (const float*)d_in[1];
  const float* gn_b   = (const float*)d_in[2];
  const float* qkv_w  = (const float*)d_in[3];
  const float* qkv_b  = (const float*)d_in[4];
  const float* proj_w = (const float*)d_in[5];
  const float* proj_b = (const float*)d_in[6];
  float* out = (float*)d_out;

  char* ws = (char*)d_ws;
  float* stats = (float*)(ws + 0);            // 128*2 fp32
  u16* qwb = (u16*)(ws + 4096);               // 768*256 bf16
  u16* pwb = (u16*)(ws + 397312);             // 256*256 bf16
  u16* qdn = (u16*)(ws + 8916992);            // [64bh][64d][1024n] bf16
  u16* knd = (u16*)(ws + 17305600);           // [64bh][1024n][64d] bf16
  u16* vdn = (u16*)(ws + 25694208);           // [64bh][64d][1024n] bf16
  u16* att = (u16*)(ws + 34082816);           // [16][1024][256] bf16

  prep<<<384, 256, 0, stream>>>(qkv_w, proj_w, x, qwb, pwb, stats);
  gemm_qkv<<<768, 256, 0, stream>>>(qwb, x, stats, gn_w, gn_b, qkv_b,
                                    qdn, knd, vdn);
  attn_fused<<<1024, 256, 0, stream>>>(qdn, knd, vdn, att);
  gemm_proj<<<dim3(128, 4), 256, 0, stream>>>(pwb, att, proj_b, x, out);
}

// Round 9
// 138.880 us; speedup vs baseline: 1.3381x; 1.0079x over previous
//
#include <hip/hip_runtime.h>

typedef unsigned short u16;
typedef __bf16 bf16x8 __attribute__((ext_vector_type(8)));
typedef float f32x4 __attribute__((ext_vector_type(4)));

// Problem constants: B=16, C=256, H=W=32 -> N=1024, heads=4, Dh=64, groups=8
// scale = 1/sqrt(64) = 0.125; fold log2(e) so softmax uses exp2 (v_exp_f32).
#define QSCALE 0.18033688011112042f  // 0.125 * log2(e)

__device__ __forceinline__ u16 f2bf(float f) {
  __bf16 h = (__bf16)f;  // RNE
  union { __bf16 b; u16 u; } cv;
  cv.b = h;
  return cv.u;
}
__device__ __forceinline__ unsigned pack2(float a, float b) {
#if __has_builtin(__builtin_amdgcn_cvt_pk_bf16_f32)
  typedef __bf16 bf16x2 __attribute__((ext_vector_type(2)));
  bf16x2 p = __builtin_amdgcn_cvt_pk_bf16_f32(a, b);
  union { bf16x2 v; unsigned u; } cv;
  cv.v = p;
  return cv.u;
#else
  return (unsigned)f2bf(a) | ((unsigned)f2bf(b) << 16);
#endif
}
__device__ __forceinline__ float fexp2(float x) {
  return __builtin_amdgcn_exp2f(x);  // raw v_exp_f32; inputs well in-range
}
// async global -> LDS DMA, 16 B per lane (dest = wave-uniform base + lane*16)
__device__ __forceinline__ void cp16(const u16* g, u16* l) {
  __builtin_amdgcn_global_load_lds(
      (const __attribute__((address_space(1))) void*)g,
      (__attribute__((address_space(3))) void*)l, 16, 0, 0);
}

// ---------------------------------------------------------------------------
// prep: blocks 0..255 convert weights fp32->bf16; blocks 256..383 gn stats.
__global__ __launch_bounds__(256) void prep(
    const float* __restrict__ qw, const float* __restrict__ pw,
    const float* __restrict__ x,
    u16* __restrict__ qwb, u16* __restrict__ pwb, float* __restrict__ stats) {
  __shared__ float sh1[256], sh2[256];
  const int blk = blockIdx.x;
  const int t = threadIdx.x;
  if (blk < 256) {
    int i = blk * 256 + t;
    const float* s; u16* d; int j;
    if (i < 49152) { s = qw; d = qwb; j = i; }
    else           { s = pw; d = pwb; j = i - 49152; }
    float4 v = *(const float4*)(s + (size_t)j * 4);
    uint2 o; o.x = pack2(v.x, v.y); o.y = pack2(v.z, v.w);
    *(uint2*)(d + (size_t)j * 4) = o;
    return;
  }
  const int bid = blk - 256;  // b*8+g
  int cl = t >> 3;
  int off = (t & 7) * 4;
  const float* p = x + (size_t)bid * 32768 + (size_t)cl * 1024 + off;
  float s = 0.f, ss = 0.f;
#pragma unroll 8
  for (int i = 0; i < 32; ++i) {
    float4 v = *(const float4*)(p + i * 32);
    s += v.x + v.y + v.z + v.w;
    ss += v.x * v.x + v.y * v.y + v.z * v.z + v.w * v.w;
  }
  sh1[t] = s; sh2[t] = ss;
  __syncthreads();
  for (int st = 128; st > 0; st >>= 1) {
    if (t < st) { sh1[t] += sh1[t + st]; sh2[t] += sh2[t + st]; }
    __syncthreads();
  }
  if (t == 0) {
    float mean = sh1[0] * (1.f / 32768.f);
    float var = sh2[0] * (1.f / 32768.f) - mean * mean;
    stats[bid * 2] = mean;
    stats[bid * 2 + 1] = rsqrtf(var + 1e-5f);
  }
}

// ---------------------------------------------------------------------------
// QKV GEMM with FUSED GroupNorm. Epilogue now writes q/k/v in CHUNKED,
// XOR-SWIZZLED LDS-image layouts so attn can stage them with raw
// global_load_lds (linear lane mapping):
//   q: [bh][qtile(n>>6)][jl=n&63][64d swizzled]  (ushort4 stores)
//   k: [bh][jchunk   ][jl     ][64d swizzled]    (ushort4 stores)
//   v: [bh][jchunk   ][d      ][64j swizzled]    (b16 stores, as before)
// Image element (row, col): off = row*64 + ((col>>3 ^ (row&7))*8) + (col&7).
__global__ __launch_bounds__(256) void gemm_qkv(
    const u16* __restrict__ A, const float* __restrict__ x,
    const float* __restrict__ stats,
    const float* __restrict__ gw, const float* __restrict__ gb,
    const float* __restrict__ bias,
    u16* __restrict__ o_q, u16* __restrict__ o_k, u16* __restrict__ o_v) {
  const int l = blockIdx.x;        // 768
  const int xcd = l & 7;
  const int i2 = l >> 3;           // 0..95
  const int m_t = i2 % 6;
  const int nl6 = i2 / 6;          // 0..15
  const int nt = xcd * 16 + nl6;   // n-tile 0..127
  const int m0 = m_t * 128;
  const int n0 = nt * 128;
  const int b = nt >> 3;
  const int nsp0 = (nt & 7) * 128;

  const int t = threadIdx.x;
  const int wave = t >> 6, lane = t & 63, lm = lane & 15, quad = lane >> 4;
  const int wr = wave >> 1, wc = wave & 1;

  __shared__ u16 As[2][128 * 32];
  __shared__ u16 Bs[2][128 * 32];

  f32x4 acc[4][4];
  const f32x4 fzero = {0.f, 0.f, 0.f, 0.f};
#pragma unroll
  for (int i = 0; i < 4; ++i)
#pragma unroll
    for (int j = 0; j < 4; ++j) acc[i][j] = fzero;

  // A staging (weights, bf16 row-major [768][256])
  const int srow = t >> 2, scol = (t & 3) * 8;
  const u16* pA0 = A + (size_t)(m0 + srow) * 256 + scol;
  const u16* pA1 = A + (size_t)(m0 + 64 + srow) * 256 + scol;

  // B staging: thread owns n-pair 2*n2, 2*n2+1 and c-granule gq (wave-uniform)
  const int n2 = t & 63, gq = t >> 6;
  const float* xb = x + (size_t)b * 262144 + nsp0 + 2 * n2;
  const int gsw = (gq ^ (n2 & 3)) * 8;  // swizzled granule offset (u16)

  float2 vB[8];
  uint4 vA0, vA1;

#define LD_B(ki)                                                       \
  {                                                                    \
    const int cb = (ki) * 32 + gq * 8;                                 \
    _Pragma("unroll") for (int i = 0; i < 8; ++i)                      \
        vB[i] = *(const float2*)(xb + (size_t)(cb + i) * 1024);        \
  }
#define ST_B(ki, buf)                                                  \
  {                                                                    \
    const int cb = (ki) * 32 + gq * 8;                                 \
    const float mu = stats[(b * 8 + (ki)) * 2];                        \
    const float rq = stats[(b * 8 + (ki)) * 2 + 1];                    \
    float e0[8], e1[8];                                                \
    _Pragma("unroll") for (int i = 0; i < 8; ++i) {                    \
      const float w = gw[cb + i] * rq;                                 \
      const float bb = gb[cb + i] - mu * w;                            \
      e0[i] = vB[i].x * w + bb;                                        \
      e1[i] = vB[i].y * w + bb;                                        \
    }                                                                  \
    uint4 w0, w1;                                                      \
    w0.x = pack2(e0[0], e0[1]); w0.y = pack2(e0[2], e0[3]);            \
    w0.z = pack2(e0[4], e0[5]); w0.w = pack2(e0[6], e0[7]);            \
    w1.x = pack2(e1[0], e1[1]); w1.y = pack2(e1[2], e1[3]);            \
    w1.z = pack2(e1[4], e1[5]); w1.w = pack2(e1[6], e1[7]);            \
    *(uint4*)(Bs[buf] + (2 * n2) * 32 + gsw) = w0;                     \
    *(uint4*)(Bs[buf] + (2 * n2 + 1) * 32 + gsw) = w1;                 \
  }

  // k-step 0 staged, k-step 1 prefetched to regs
  LD_B(0);
  vA0 = *(const uint4*)pA0;
  vA1 = *(const uint4*)pA1;
  ST_B(0, 0);
  *(uint4*)(As[0] + srow * 32 + scol) = vA0;
  *(uint4*)(As[0] + (64 + srow) * 32 + scol) = vA1;
  LD_B(1);
  vA0 = *(const uint4*)(pA0 + 32);
  vA1 = *(const uint4*)(pA1 + 32);

  for (int ki = 0; ki < 8; ++ki) {
    __syncthreads();
    if (ki + 1 < 8) {
      ST_B(ki + 1, (ki + 1) & 1);
      u16* as = As[(ki + 1) & 1];
      *(uint4*)(as + srow * 32 + scol) = vA0;
      *(uint4*)(as + (64 + srow) * 32 + scol) = vA1;
    }
    if (ki + 2 < 8) {
      LD_B(ki + 2);
      vA0 = *(const uint4*)(pA0 + (ki + 2) * 32);
      vA1 = *(const uint4*)(pA1 + (ki + 2) * 32);
    }
    const u16* as = As[ki & 1];
    const u16* bs = Bs[ki & 1];
    bf16x8 af[4], bf[4];
#pragma unroll
    for (int mb = 0; mb < 4; ++mb)
      af[mb] = *(const bf16x8*)(as + (wr * 64 + mb * 16 + lm) * 32 + quad * 8);
#pragma unroll
    for (int nb = 0; nb < 4; ++nb) {
      const int row = wc * 64 + nb * 16 + lm;
      bf[nb] = *(const bf16x8*)(bs + row * 32 + ((quad ^ ((row >> 1) & 3)) * 8));
    }
#pragma unroll
    for (int mb = 0; mb < 4; ++mb)
#pragma unroll
      for (int nb = 0; nb < 4; ++nb)
        acc[mb][nb] = __builtin_amdgcn_mfma_f32_16x16x32_bf16(af[mb], bf[nb],
                                                              acc[mb][nb], 0, 0, 0);
  }
#undef LD_B
#undef ST_B

#pragma unroll
  for (int mb = 0; mb < 4; ++mb) {
#pragma unroll
    for (int nb = 0; nb < 4; ++nb) {
      const int o = m0 + wr * 64 + mb * 16 + 4 * quad;  // +r along m
      const int ng = n0 + wc * 64 + nb * 16 + lm;
      const int bb = ng >> 10, n = ng & 1023;
      const int kind = o >> 8;  // uniform per mb
      const int h = (o >> 6) & 3;
      const int dd = o & 63;          // dd&7 in {0,4}: r=0..3 stays in granule
      const int jc = n >> 6, jl = n & 63;
      const size_t bhoff = ((size_t)(bb * 4 + h)) * 65536 + jc * 4096;
      if (kind <= 1) {  // q / k -> row=jl, col=d (swizzled), ushort4
        const float sc = (kind == 0) ? QSCALE : 1.f;
        u16* base = (kind == 0) ? o_q : o_k;
        ushort4 pq;
        pq.x = f2bf((acc[mb][nb][0] + bias[o]) * sc);
        pq.y = f2bf((acc[mb][nb][1] + bias[o + 1]) * sc);
        pq.z = f2bf((acc[mb][nb][2] + bias[o + 2]) * sc);
        pq.w = f2bf((acc[mb][nb][3] + bias[o + 3]) * sc);
        *(ushort4*)(base + bhoff + jl * 64 + (((dd >> 3) ^ (jl & 7)) * 8) +
                    (dd & 7)) = pq;
      } else {  // v -> row=d, col=j (swizzled), b16 stores
        u16* vbase = o_v + bhoff + (jl & 7);
#pragma unroll
        for (int r = 0; r < 4; ++r) {
          const int d = dd + r;
          vbase[d * 64 + (((jl >> 3) ^ (d & 7)) * 8)] =
              f2bf(acc[mb][nb][r] + bias[o + r]);
        }
      }
    }
  }
}

// ---------------------------------------------------------------------------
// Proj NT bf16 GEMM, 64m x 128n tile (512 blocks -> multi-block residency).
// Epilogue: +bias +skip -> fp32 out.
__global__ __launch_bounds__(256) void gemm_proj(
    const u16* __restrict__ A, const u16* __restrict__ Bm,
    const float* __restrict__ bias,
    const float* __restrict__ skip, float* __restrict__ out) {
  const int m0 = blockIdx.y * 64;
  const int n0 = blockIdx.x * 128;
  const int t = threadIdx.x;
  const int wave = t >> 6, lane = t & 63, lm = lane & 15, quad = lane >> 4;
  const int wr = wave >> 1, wc = wave & 1;

  __shared__ u16 As[2][64 * 32];
  __shared__ u16 Bs[2][128 * 32];

  f32x4 acc[2][4];
  const f32x4 fzero = {0.f, 0.f, 0.f, 0.f};
#pragma unroll
  for (int i = 0; i < 2; ++i)
#pragma unroll
    for (int j = 0; j < 4; ++j) acc[i][j] = fzero;

  const int srow = t >> 2, scol = (t & 3) * 8;
  const u16* pA0 = A + (size_t)(m0 + srow) * 256 + scol;
  const u16* pB0 = Bm + (size_t)(n0 + srow) * 256 + scol;
  const u16* pB1 = Bm + (size_t)(n0 + 64 + srow) * 256 + scol;

  uint4 pa0 = *(const uint4*)pA0;
  uint4 pb0 = *(const uint4*)pB0;
  uint4 pb1 = *(const uint4*)pB1;
  *(uint4*)(As[0] + srow * 32 + scol) = pa0;
  *(uint4*)(Bs[0] + srow * 32 + scol) = pb0;
  *(uint4*)(Bs[0] + (64 + srow) * 32 + scol) = pb1;
  pa0 = *(const uint4*)(pA0 + 32);
  pb0 = *(const uint4*)(pB0 + 32);
  pb1 = *(const uint4*)(pB1 + 32);

  for (int ki = 0; ki < 8; ++ki) {
    __syncthreads();
    if (ki + 1 < 8) {
      u16* as = As[(ki + 1) & 1];
      u16* bs = Bs[(ki + 1) & 1];
      *(uint4*)(as + srow * 32 + scol) = pa0;
      *(uint4*)(bs + srow * 32 + scol) = pb0;
      *(uint4*)(bs + (64 + srow) * 32 + scol) = pb1;
    }
    if (ki + 2 < 8) {
      const int ko = (ki + 2) * 32;
      pa0 = *(const uint4*)(pA0 + ko);
      pb0 = *(const uint4*)(pB0 + ko);
      pb1 = *(const uint4*)(pB1 + ko);
    }
    const u16* as = As[ki & 1];
    const u16* bs = Bs[ki & 1];
    bf16x8 af[2], bf[4];
#pragma unroll
    for (int mb = 0; mb < 2; ++mb)
      af[mb] = *(const bf16x8*)(as + (wr * 32 + mb * 16 + lm) * 32 + quad * 8);
#pragma unroll
    for (int nb = 0; nb < 4; ++nb)
      bf[nb] = *(const bf16x8*)(bs + (wc * 64 + nb * 16 + lm) * 32 + quad * 8);
#pragma unroll
    for (int mb = 0; mb < 2; ++mb)
#pragma unroll
      for (int nb = 0; nb < 4; ++nb)
        acc[mb][nb] = __builtin_amdgcn_mfma_f32_16x16x32_bf16(af[mb], bf[nb],
                                                              acc[mb][nb], 0, 0, 0);
  }

#pragma unroll
  for (int mb = 0; mb < 2; ++mb) {
#pragma unroll
    for (int nb = 0; nb < 4; ++nb) {
      const int o = m0 + wr * 32 + mb * 16 + 4 * quad;
      const int ng = n0 + wc * 64 + nb * 16 + lm;
      const int b = ng >> 10, n = ng & 1023;
#pragma unroll
      for (int r = 0; r < 4; ++r) {
        const size_t oi = ((size_t)(b * 256 + o + r)) * 1024 + n;
        out[oi] = acc[mb][nb][r] + bias[o + r] + skip[oi];
      }
    }
  }
}

// ---------------------------------------------------------------------------
// Flash attention v9 = v8 shape (256 thr, 16 rows/wave, grid 1024, 40 KB LDS
// -> 4 blocks/CU) with K/V/Q staging via global_load_lds width=16: producer
// (gemm_qkv) pre-baked the XOR-swizzled LDS images in global memory, so the
// DMA's linear lane mapping lands the swizzle for free. No staging VGPRs, no
// ds_write instructions, no in-kernel Q transpose; loads for chunk jc+1 are
// issued right after the barrier and stay in flight across chunk jc's compute
// (drained by the next __syncthreads' vmcnt(0)).
__global__ __launch_bounds__(256) void attn_fused(
    const u16* __restrict__ qsw, const u16* __restrict__ ksw,
    const u16* __restrict__ vsw, u16* __restrict__ att) {
  const int bid = blockIdx.x;  // 1024
  const int bh = (bid & 7) * 8 + ((bid >> 3) & 7);  // 8 bh per XCD
  const int qtile = bid >> 6;                       // 0..15
  const int t = threadIdx.x;
  const int wave = t >> 6, lane = t & 63, lm = lane & 15, quad = lane >> 4;

  const u16* qb = qsw + (size_t)bh * 65536 + qtile * 4096;
  const u16* kb = ksw + (size_t)bh * 65536;
  const u16* vb = vsw + (size_t)bh * 65536;

  __shared__ u16 KV[2][2][4096];  // 32768 B (dbuf x {K,V} images)
  __shared__ u16 QP[4096];        // 8192 B; Q image, then per-wave P slices

  const int t8 = t * 8;  // 16 B per lane

  // Q (8 KB) + chunk 0 K/V into buf 0
  cp16(qb + t8, QP + t8);
  cp16(qb + 2048 + t8, QP + 2048 + t8);
  cp16(kb + t8, KV[0][0] + t8);
  cp16(kb + 2048 + t8, KV[0][0] + 2048 + t8);
  cp16(vb + t8, KV[0][1] + t8);
  cp16(vb + 2048 + t8, KV[0][1] + 2048 + t8);
  __syncthreads();

  const int swz0 = (quad ^ (lm & 7)) * 8;
  const int swz1 = ((4 + quad) ^ (lm & 7)) * 8;
  u16* Pw = QP + (wave * 16 + lm) * 64;
  const bf16x8 qf0 = *(const bf16x8*)(Pw + swz0);
  const bf16x8 qf1 = *(const bf16x8*)(Pw + swz1);

  const f32x4 fzero = {0.f, 0.f, 0.f, 0.f};
  f32x4 oacc[4];
#pragma unroll
  for (int d = 0; d < 4; ++d) oacc[d] = fzero;
  float lp = 0.f;

  for (int jc = 0; jc < 16; ++jc) {
    if (jc) __syncthreads();  // drains chunk jc's DMA + prev buf's frag reads
    if (jc + 1 < 16) {        // DMA chunk jc+1 into the other buffer
      const int base = (jc + 1) * 4096;
      u16* kd = KV[(jc + 1) & 1][0];
      u16* vd = KV[(jc + 1) & 1][1];
      cp16(kb + base + t8, kd + t8);
      cp16(kb + base + 2048 + t8, kd + 2048 + t8);
      cp16(vb + base + t8, vd + t8);
      cp16(vb + base + 2048 + t8, vd + 2048 + t8);
    }
    const u16* Ks = KV[jc & 1][0];
    const u16* Vs = KV[jc & 1][1];

    f32x4 sacc[4];
#pragma unroll
    for (int jb = 0; jb < 4; ++jb) sacc[jb] = fzero;
#pragma unroll
    for (int jb = 0; jb < 4; ++jb) {
      const int row = (jb * 16 + lm) * 64;
      bf16x8 kf0 = *(const bf16x8*)(Ks + row + swz0);
      bf16x8 kf1 = *(const bf16x8*)(Ks + row + swz1);
      sacc[jb] = __builtin_amdgcn_mfma_f32_16x16x32_bf16(kf0, qf0, sacc[jb], 0, 0, 0);
      sacc[jb] = __builtin_amdgcn_mfma_f32_16x16x32_bf16(kf1, qf1, sacc[jb], 0, 0, 0);
    }
    // P: row i=lm, 4 j-contiguous values per (jb,quad) -> b64 writes
#pragma unroll
    for (int jb = 0; jb < 4; ++jb) {
      const float e0 = fexp2(sacc[jb][0]);
      const float e1_ = fexp2(sacc[jb][1]);
      const float e2 = fexp2(sacc[jb][2]);
      const float e3 = fexp2(sacc[jb][3]);
      lp += (e0 + e1_) + (e2 + e3);
      uint2 pw;
      pw.x = pack2(e0, e1_);
      pw.y = pack2(e2, e3);
      const int oct = 2 * jb + (quad >> 1);
      *(uint2*)(Pw + ((oct ^ (lm & 7)) * 8) + 4 * (quad & 1)) = pw;
    }
    bf16x8 pf0 = *(const bf16x8*)(Pw + swz0);
    bf16x8 pf1 = *(const bf16x8*)(Pw + swz1);
#pragma unroll
    for (int db = 0; db < 4; ++db) {
      const int row = (db * 16 + lm) * 64;
      bf16x8 vf0 = *(const bf16x8*)(Vs + row + swz0);
      bf16x8 vf1 = *(const bf16x8*)(Vs + row + swz1);
      oacc[db] = __builtin_amdgcn_mfma_f32_16x16x32_bf16(pf0, vf0, oacc[db], 0, 0, 0);
      oacc[db] = __builtin_amdgcn_mfma_f32_16x16x32_bf16(pf1, vf1, oacc[db], 0, 0, 0);
    }
  }

  // epilogue: full row-sums via 2 shuffles, normalize, store.
  float rs = lp;
  rs += __shfl_xor(rs, 16);
  rs += __shfl_xor(rs, 32);
  const int b = bh >> 2, h = bh & 3;
#pragma unroll
  for (int r = 0; r < 4; ++r) {
    const float inv = 1.f / __shfl(rs, 4 * quad + r);
    const int n = qtile * 64 + wave * 16 + 4 * quad + r;
#pragma unroll
    for (int db = 0; db < 4; ++db) {
      const int c = h * 64 + db * 16 + lm;
      att[((size_t)(b * 1024 + n)) * 256 + c] = f2bf(oacc[db][r] * inv);
    }
  }
}

// ---------------------------------------------------------------------------
extern "C" void kernel_launch(void* const* d_in, const int* in_sizes, int n_in,
                              void* d_out, int out_size, void* d_ws, size_t ws_size,
                              hipStream_t stream) {
  const float* x      = (const float*)d_in[0];
  const float* gn_w   = (const float*)d_in[1];
  const float* gn_b   = (const float*)d_in[2];
  const float* qkv_w  = (const float*)d_in[3];
  const float* qkv_b  = (const float*)d_in[4];
  const float* proj_w = (const float*)d_in[5];
  const float* proj_b = (const float*)d_in[6];
  float* out = (float*)d_out;

  char* ws = (char*)d_ws;
  float* stats = (float*)(ws + 0);            // 128*2 fp32
  u16* qwb = (u16*)(ws + 4096);               // 768*256 bf16
  u16* pwb = (u16*)(ws + 397312);             // 256*256 bf16
  u16* qsw = (u16*)(ws + 8916992);            // [64bh][16qt][64x64 swz image]
  u16* ksw = (u16*)(ws + 17305600);           // [64bh][16jc][64x64 swz image]
  u16* vsw = (u16*)(ws + 25694208);           // [64bh][16jc][64x64 swz image]
  u16* att = (u16*)(ws + 34082816);           // [16][1024][256] bf16

  prep<<<384, 256, 0, stream>>>(qkv_w, proj_w, x, qwb, pwb, stats);
  gemm_qkv<<<768, 256, 0, stream>>>(qwb, x, stats, gn_w, gn_b, qkv_b,
                                    qsw, ksw, vsw);
  attn_fused<<<1024, 256, 0, stream>>>(qsw, ksw, vsw, att);
  gemm_proj<<<dim3(128, 4), 256, 0, stream>>>(pwb, att, proj_b, x, out);
}

// Round 10
// 138.299 us; speedup vs baseline: 1.3437x; 1.0042x over previous
//
#include <hip/hip_runtime.h>

typedef unsigned short u16;
typedef __bf16 bf16x8 __attribute__((ext_vector_type(8)));
typedef float f32x4 __attribute__((ext_vector_type(4)));
typedef float f32x16 __attribute__((ext_vector_type(16)));

// Problem constants: B=16, C=256, H=W=32 -> N=1024, heads=4, Dh=64, groups=8
// scale = 1/sqrt(64) = 0.125; fold log2(e) so softmax uses exp2 (v_exp_f32).
#define QSCALE 0.18033688011112042f  // 0.125 * log2(e)

__device__ __forceinline__ u16 f2bf(float f) {
  __bf16 h = (__bf16)f;  // RNE
  union { __bf16 b; u16 u; } cv;
  cv.b = h;
  return cv.u;
}
__device__ __forceinline__ unsigned pack2(float a, float b) {
#if __has_builtin(__builtin_amdgcn_cvt_pk_bf16_f32)
  typedef __bf16 bf16x2 __attribute__((ext_vector_type(2)));
  bf16x2 p = __builtin_amdgcn_cvt_pk_bf16_f32(a, b);
  union { bf16x2 v; unsigned u; } cv;
  cv.v = p;
  return cv.u;
#else
  return (unsigned)f2bf(a) | ((unsigned)f2bf(b) << 16);
#endif
}
__device__ __forceinline__ float fexp2(float x) {
  return __builtin_amdgcn_exp2f(x);  // raw v_exp_f32; inputs well in-range
}
// async global -> LDS DMA, 16 B per lane (dest = wave-uniform base + lane*16)
__device__ __forceinline__ void cp16(const u16* g, u16* l) {
  __builtin_amdgcn_global_load_lds(
      (const __attribute__((address_space(1))) void*)g,
      (__attribute__((address_space(3))) void*)l, 16, 0, 0);
}

// ---------------------------------------------------------------------------
// prep: blocks 0..255 convert weights fp32->bf16; blocks 256..383 gn stats.
__global__ __launch_bounds__(256) void prep(
    const float* __restrict__ qw, const float* __restrict__ pw,
    const float* __restrict__ x,
    u16* __restrict__ qwb, u16* __restrict__ pwb, float* __restrict__ stats) {
  __shared__ float sh1[256], sh2[256];
  const int blk = blockIdx.x;
  const int t = threadIdx.x;
  if (blk < 256) {
    int i = blk * 256 + t;
    const float* s; u16* d; int j;
    if (i < 49152) { s = qw; d = qwb; j = i; }
    else           { s = pw; d = pwb; j = i - 49152; }
    float4 v = *(const float4*)(s + (size_t)j * 4);
    uint2 o; o.x = pack2(v.x, v.y); o.y = pack2(v.z, v.w);
    *(uint2*)(d + (size_t)j * 4) = o;
    return;
  }
  const int bid = blk - 256;  // b*8+g
  int cl = t >> 3;
  int off = (t & 7) * 4;
  const float* p = x + (size_t)bid * 32768 + (size_t)cl * 1024 + off;
  float s = 0.f, ss = 0.f;
#pragma unroll 8
  for (int i = 0; i < 32; ++i) {
    float4 v = *(const float4*)(p + i * 32);
    s += v.x + v.y + v.z + v.w;
    ss += v.x * v.x + v.y * v.y + v.z * v.z + v.w * v.w;
  }
  sh1[t] = s; sh2[t] = ss;
  __syncthreads();
  for (int st = 128; st > 0; st >>= 1) {
    if (t < st) { sh1[t] += sh1[t + st]; sh2[t] += sh2[t + st]; }
    __syncthreads();
  }
  if (t == 0) {
    float mean = sh1[0] * (1.f / 32768.f);
    float var = sh2[0] * (1.f / 32768.f) - mean * mean;
    stats[bid * 2] = mean;
    stats[bid * 2 + 1] = rsqrtf(var + 1e-5f);
  }
}

// ---------------------------------------------------------------------------
// QKV GEMM with FUSED GroupNorm. Epilogue writes q/k/v as CHUNKED,
// XOR-SWIZZLED LDS images for attn's global_load_lds staging:
//   q: [bh][qtile][64n x 64d image]   k: [bh][jchunk][64j x 64d image]
//   v: [bh][jchunk][64d x 64j image]
// Image element (row, col): off = row*64 + ((col>>3 ^ (row&7))*8) + (col&7).
__global__ __launch_bounds__(256) void gemm_qkv(
    const u16* __restrict__ A, const float* __restrict__ x,
    const float* __restrict__ stats,
    const float* __restrict__ gw, const float* __restrict__ gb,
    const float* __restrict__ bias,
    u16* __restrict__ o_q, u16* __restrict__ o_k, u16* __restrict__ o_v) {
  const int l = blockIdx.x;        // 768
  const int xcd = l & 7;
  const int i2 = l >> 3;           // 0..95
  const int m_t = i2 % 6;
  const int nl6 = i2 / 6;          // 0..15
  const int nt = xcd * 16 + nl6;   // n-tile 0..127
  const int m0 = m_t * 128;
  const int n0 = nt * 128;
  const int b = nt >> 3;
  const int nsp0 = (nt & 7) * 128;

  const int t = threadIdx.x;
  const int wave = t >> 6, lane = t & 63, lm = lane & 15, quad = lane >> 4;
  const int wr = wave >> 1, wc = wave & 1;

  __shared__ u16 As[2][128 * 32];
  __shared__ u16 Bs[2][128 * 32];

  f32x4 acc[4][4];
  const f32x4 fzero = {0.f, 0.f, 0.f, 0.f};
#pragma unroll
  for (int i = 0; i < 4; ++i)
#pragma unroll
    for (int j = 0; j < 4; ++j) acc[i][j] = fzero;

  const int srow = t >> 2, scol = (t & 3) * 8;
  const u16* pA0 = A + (size_t)(m0 + srow) * 256 + scol;
  const u16* pA1 = A + (size_t)(m0 + 64 + srow) * 256 + scol;

  const int n2 = t & 63, gq = t >> 6;
  const float* xb = x + (size_t)b * 262144 + nsp0 + 2 * n2;
  const int gsw = (gq ^ (n2 & 3)) * 8;

  float2 vB[8];
  uint4 vA0, vA1;

#define LD_B(ki)                                                       \
  {                                                                    \
    const int cb = (ki) * 32 + gq * 8;                                 \
    _Pragma("unroll") for (int i = 0; i < 8; ++i)                      \
        vB[i] = *(const float2*)(xb + (size_t)(cb + i) * 1024);        \
  }
#define ST_B(ki, buf)                                                  \
  {                                                                    \
    const int cb = (ki) * 32 + gq * 8;                                 \
    const float mu = stats[(b * 8 + (ki)) * 2];                        \
    const float rq = stats[(b * 8 + (ki)) * 2 + 1];                    \
    float e0[8], e1[8];                                                \
    _Pragma("unroll") for (int i = 0; i < 8; ++i) {                    \
      const float w = gw[cb + i] * rq;                                 \
      const float bb = gb[cb + i] - mu * w;                            \
      e0[i] = vB[i].x * w + bb;                                        \
      e1[i] = vB[i].y * w + bb;                                        \
    }                                                                  \
    uint4 w0, w1;                                                      \
    w0.x = pack2(e0[0], e0[1]); w0.y = pack2(e0[2], e0[3]);            \
    w0.z = pack2(e0[4], e0[5]); w0.w = pack2(e0[6], e0[7]);            \
    w1.x = pack2(e1[0], e1[1]); w1.y = pack2(e1[2], e1[3]);            \
    w1.z = pack2(e1[4], e1[5]); w1.w = pack2(e1[6], e1[7]);            \
    *(uint4*)(Bs[buf] + (2 * n2) * 32 + gsw) = w0;                     \
    *(uint4*)(Bs[buf] + (2 * n2 + 1) * 32 + gsw) = w1;                 \
  }

  LD_B(0);
  vA0 = *(const uint4*)pA0;
  vA1 = *(const uint4*)pA1;
  ST_B(0, 0);
  *(uint4*)(As[0] + srow * 32 + scol) = vA0;
  *(uint4*)(As[0] + (64 + srow) * 32 + scol) = vA1;
  LD_B(1);
  vA0 = *(const uint4*)(pA0 + 32);
  vA1 = *(const uint4*)(pA1 + 32);

  for (int ki = 0; ki < 8; ++ki) {
    __syncthreads();
    if (ki + 1 < 8) {
      ST_B(ki + 1, (ki + 1) & 1);
      u16* as = As[(ki + 1) & 1];
      *(uint4*)(as + srow * 32 + scol) = vA0;
      *(uint4*)(as + (64 + srow) * 32 + scol) = vA1;
    }
    if (ki + 2 < 8) {
      LD_B(ki + 2);
      vA0 = *(const uint4*)(pA0 + (ki + 2) * 32);
      vA1 = *(const uint4*)(pA1 + (ki + 2) * 32);
    }
    const u16* as = As[ki & 1];
    const u16* bs = Bs[ki & 1];
    bf16x8 af[4], bf[4];
#pragma unroll
    for (int mb = 0; mb < 4; ++mb)
      af[mb] = *(const bf16x8*)(as + (wr * 64 + mb * 16 + lm) * 32 + quad * 8);
#pragma unroll
    for (int nb = 0; nb < 4; ++nb) {
      const int row = wc * 64 + nb * 16 + lm;
      bf[nb] = *(const bf16x8*)(bs + row * 32 + ((quad ^ ((row >> 1) & 3)) * 8));
    }
#pragma unroll
    for (int mb = 0; mb < 4; ++mb)
#pragma unroll
      for (int nb = 0; nb < 4; ++nb)
        acc[mb][nb] = __builtin_amdgcn_mfma_f32_16x16x32_bf16(af[mb], bf[nb],
                                                              acc[mb][nb], 0, 0, 0);
  }
#undef LD_B
#undef ST_B

#pragma unroll
  for (int mb = 0; mb < 4; ++mb) {
#pragma unroll
    for (int nb = 0; nb < 4; ++nb) {
      const int o = m0 + wr * 64 + mb * 16 + 4 * quad;  // +r along m
      const int ng = n0 + wc * 64 + nb * 16 + lm;
      const int bb = ng >> 10, n = ng & 1023;
      const int kind = o >> 8;  // uniform per mb
      const int h = (o >> 6) & 3;
      const int dd = o & 63;
      const int jc = n >> 6, jl = n & 63;
      const size_t bhoff = ((size_t)(bb * 4 + h)) * 65536 + jc * 4096;
      if (kind <= 1) {  // q / k -> row=jl, col=d (swizzled), ushort4
        const float sc = (kind == 0) ? QSCALE : 1.f;
        u16* base = (kind == 0) ? o_q : o_k;
        ushort4 pq;
        pq.x = f2bf((acc[mb][nb][0] + bias[o]) * sc);
        pq.y = f2bf((acc[mb][nb][1] + bias[o + 1]) * sc);
        pq.z = f2bf((acc[mb][nb][2] + bias[o + 2]) * sc);
        pq.w = f2bf((acc[mb][nb][3] + bias[o + 3]) * sc);
        *(ushort4*)(base + bhoff + jl * 64 + (((dd >> 3) ^ (jl & 7)) * 8) +
                    (dd & 7)) = pq;
      } else {  // v -> row=d, col=j (swizzled), b16 stores
        u16* vbase = o_v + bhoff + (jl & 7);
#pragma unroll
        for (int r = 0; r < 4; ++r) {
          const int d = dd + r;
          vbase[d * 64 + (((jl >> 3) ^ (d & 7)) * 8)] =
              f2bf(acc[mb][nb][r] + bias[o + r]);
        }
      }
    }
  }
}

// ---------------------------------------------------------------------------
// Proj NT bf16 GEMM, 64m x 128n tile. Epilogue: +bias +skip -> fp32 out.
__global__ __launch_bounds__(256) void gemm_proj(
    const u16* __restrict__ A, const u16* __restrict__ Bm,
    const float* __restrict__ bias,
    const float* __restrict__ skip, float* __restrict__ out) {
  const int m0 = blockIdx.y * 64;
  const int n0 = blockIdx.x * 128;
  const int t = threadIdx.x;
  const int wave = t >> 6, lane = t & 63, lm = lane & 15, quad = lane >> 4;
  const int wr = wave >> 1, wc = wave & 1;

  __shared__ u16 As[2][64 * 32];
  __shared__ u16 Bs[2][128 * 32];

  f32x4 acc[2][4];
  const f32x4 fzero = {0.f, 0.f, 0.f, 0.f};
#pragma unroll
  for (int i = 0; i < 2; ++i)
#pragma unroll
    for (int j = 0; j < 4; ++j) acc[i][j] = fzero;

  const int srow = t >> 2, scol = (t & 3) * 8;
  const u16* pA0 = A + (size_t)(m0 + srow) * 256 + scol;
  const u16* pB0 = Bm + (size_t)(n0 + srow) * 256 + scol;
  const u16* pB1 = Bm + (size_t)(n0 + 64 + srow) * 256 + scol;

  uint4 pa0 = *(const uint4*)pA0;
  uint4 pb0 = *(const uint4*)pB0;
  uint4 pb1 = *(const uint4*)pB1;
  *(uint4*)(As[0] + srow * 32 + scol) = pa0;
  *(uint4*)(Bs[0] + srow * 32 + scol) = pb0;
  *(uint4*)(Bs[0] + (64 + srow) * 32 + scol) = pb1;
  pa0 = *(const uint4*)(pA0 + 32);
  pb0 = *(const uint4*)(pB0 + 32);
  pb1 = *(const uint4*)(pB1 + 32);

  for (int ki = 0; ki < 8; ++ki) {
    __syncthreads();
    if (ki + 1 < 8) {
      u16* as = As[(ki + 1) & 1];
      u16* bs = Bs[(ki + 1) & 1];
      *(uint4*)(as + srow * 32 + scol) = pa0;
      *(uint4*)(bs + srow * 32 + scol) = pb0;
      *(uint4*)(bs + (64 + srow) * 32 + scol) = pb1;
    }
    if (ki + 2 < 8) {
      const int ko = (ki + 2) * 32;
      pa0 = *(const uint4*)(pA0 + ko);
      pb0 = *(const uint4*)(pB0 + ko);
      pb1 = *(const uint4*)(pB1 + ko);
    }
    const u16* as = As[ki & 1];
    const u16* bs = Bs[ki & 1];
    bf16x8 af[2], bf[4];
#pragma unroll
    for (int mb = 0; mb < 2; ++mb)
      af[mb] = *(const bf16x8*)(as + (wr * 32 + mb * 16 + lm) * 32 + quad * 8);
#pragma unroll
    for (int nb = 0; nb < 4; ++nb)
      bf[nb] = *(const bf16x8*)(bs + (wc * 64 + nb * 16 + lm) * 32 + quad * 8);
#pragma unroll
    for (int mb = 0; mb < 2; ++mb)
#pragma unroll
      for (int nb = 0; nb < 4; ++nb)
        acc[mb][nb] = __builtin_amdgcn_mfma_f32_16x16x32_bf16(af[mb], bf[nb],
                                                              acc[mb][nb], 0, 0, 0);
  }

#pragma unroll
  for (int mb = 0; mb < 2; ++mb) {
#pragma unroll
    for (int nb = 0; nb < 4; ++nb) {
      const int o = m0 + wr * 32 + mb * 16 + 4 * quad;
      const int ng = n0 + wc * 64 + nb * 16 + lm;
      const int b = ng >> 10, n = ng & 1023;
#pragma unroll
      for (int r = 0; r < 4; ++r) {
        const size_t oi = ((size_t)(b * 256 + o + r)) * 1024 + n;
        out[oi] = acc[mb][nb][r] + bias[o + r] + skip[oi];
      }
    }
  }
}

// ---------------------------------------------------------------------------
// Flash attention v10: 32x32x16 MFMA -> 2x FLOP per LDS frag byte (the 16x16
// structural ceiling). Block = 4 waves: wave = (i-block = wave&1, 32 rows) x
// (j-half = wave>>1, 32 of each 64-j chunk). No-max softmax makes the j-split
// combine a plain add at the END (once, through the retired KV region).
// Per chunk/block: K 16 b128 + V 16 b128 (was 32+32), P 4 b64 w + 2 b128 r
// per wave. Q image (8 KB) consumed to 4 held B-frags, area reused as per-wave
// P slices [32i][32j] pitch 32, granule ^=(i>>1)&3. O lands in C/D with d
// contiguous per reg-quad -> ushort4 stores; row-sum: 1 shfl_xor + combine.
// LDS 40960 B -> 4 blocks/CU. Staging via global_load_lds (images from qkv).
__global__ __launch_bounds__(256) void attn_fused(
    const u16* __restrict__ qsw, const u16* __restrict__ ksw,
    const u16* __restrict__ vsw, u16* __restrict__ att) {
  const int bid = blockIdx.x;  // 1024
  const int bh = (bid & 7) * 8 + ((bid >> 3) & 7);  // 8 bh per XCD
  const int qtile = bid >> 6;                       // 0..15
  const int t = threadIdx.x;
  const int wave = t >> 6, lane = t & 63;
  const int l5 = lane & 31, h = lane >> 5;
  const int iblk = wave & 1, jh = wave >> 1;

  const u16* qb = qsw + (size_t)bh * 65536 + qtile * 4096;
  const u16* kb = ksw + (size_t)bh * 65536;
  const u16* vb = vsw + (size_t)bh * 65536;

  __shared__ u16 KV[2][2][4096];  // 32768 B
  __shared__ u16 QP[4096];        // 8192 B: Q image, then per-wave P slices

  const int t8 = t * 8;
  cp16(qb + t8, QP + t8);
  cp16(qb + 2048 + t8, QP + 2048 + t8);
  cp16(kb + t8, KV[0][0] + t8);
  cp16(kb + 2048 + t8, KV[0][0] + 2048 + t8);
  cp16(vb + t8, KV[0][1] + t8);
  cp16(vb + 2048 + t8, KV[0][1] + 2048 + t8);
  __syncthreads();

  // Q B-frags: B[k=16sd+8h+jj][n=i], image row = i, col = d.
  const int qrow = iblk * 32 + l5;
  bf16x8 qf[4];
#pragma unroll
  for (int sd = 0; sd < 4; ++sd)
    qf[sd] = *(const bf16x8*)(QP + qrow * 64 + (((2 * sd + h) ^ (qrow & 7)) * 8));
  __syncthreads();  // everyone done reading Q before P slices overwrite it

  u16* Pw = QP + wave * 1024;  // [i=32][j=32] pitch 32, granule ^= (i>>1)&3
  const int pswz = (l5 >> 1) & 3;

  f32x16 oacc0, oacc1;
#pragma unroll
  for (int r = 0; r < 16; ++r) { oacc0[r] = 0.f; oacc1[r] = 0.f; }
  float lp = 0.f;

  for (int jc = 0; jc < 16; ++jc) {
    if (jc) __syncthreads();
    if (jc + 1 < 16) {
      const int base = (jc + 1) * 4096;
      u16* kd = KV[(jc + 1) & 1][0];
      u16* vd = KV[(jc + 1) & 1][1];
      cp16(kb + base + t8, kd + t8);
      cp16(kb + base + 2048 + t8, kd + 2048 + t8);
      cp16(vb + base + t8, vd + t8);
      cp16(vb + base + 2048 + t8, vd + 2048 + t8);
    }
    const u16* Ks = KV[jc & 1][0];
    const u16* Vs = KV[jc & 1][1];

    // S^T[j=32][i=32] = K(32x64) . Q^T(64x32), 4 K-steps of 16 d.
    f32x16 sacc;
#pragma unroll
    for (int r = 0; r < 16; ++r) sacc[r] = 0.f;
    const int krow = jh * 32 + l5;
    const int kswz = krow & 7;
#pragma unroll
    for (int sd = 0; sd < 4; ++sd) {
      bf16x8 kf = *(const bf16x8*)(Ks + krow * 64 + (((2 * sd + h) ^ kswz) * 8));
      sacc = __builtin_amdgcn_mfma_f32_32x32x16_bf16(kf, qf[sd], sacc, 0, 0, 0);
    }
    // exp2 + pack + P write: reg 4g+r holds j_local = r + 8g + 4h (col i=l5)
#pragma unroll
    for (int g = 0; g < 4; ++g) {
      const float e0 = fexp2(sacc[4 * g + 0]);
      const float e1 = fexp2(sacc[4 * g + 1]);
      const float e2 = fexp2(sacc[4 * g + 2]);
      const float e3 = fexp2(sacc[4 * g + 3]);
      lp += (e0 + e1) + (e2 + e3);
      uint2 pw;
      pw.x = pack2(e0, e1);
      pw.y = pack2(e2, e3);
      *(uint2*)(Pw + l5 * 32 + ((g ^ pswz) * 8) + 4 * h) = pw;
    }
    // P B-frags: B[k=j_local=16sj+8h+jj][n=i] -> granule 2sj+h of row i
    bf16x8 pf[2];
#pragma unroll
    for (int sj = 0; sj < 2; ++sj)
      pf[sj] = *(const bf16x8*)(Pw + l5 * 32 + (((2 * sj + h) ^ pswz) * 8));
    // O^T[d=64][i=32] += V^T(64 x 32j) . P^T(32j x 32i)
#pragma unroll
    for (int sj = 0; sj < 2; ++sj) {
      const int vrow0 = l5;        // db = 0
      const int vrow1 = 32 + l5;   // db = 1
      const int gv = 4 * jh + 2 * sj + h;
      bf16x8 vf0 = *(const bf16x8*)(Vs + vrow0 * 64 + ((gv ^ (vrow0 & 7)) * 8));
      bf16x8 vf1 = *(const bf16x8*)(Vs + vrow1 * 64 + ((gv ^ (vrow1 & 7)) * 8));
      oacc0 = __builtin_amdgcn_mfma_f32_32x32x16_bf16(vf0, pf[sj], oacc0, 0, 0, 0);
      oacc1 = __builtin_amdgcn_mfma_f32_32x32x16_bf16(vf1, pf[sj], oacc1, 0, 0, 0);
    }
  }

  // row-sum across the two h-halves of this wave (same i, other 16 j's)
  lp += __shfl_xor(lp, 32);

  // combine the two j-halves (plain add: unnormalized softmax partials)
  float* cb = (float*)KV[0];  // 16 KB scratch, KV retired
  __syncthreads();
  if (jh == 1) {
    float* d = cb + (iblk * 64 + lane) * 33;
#pragma unroll
    for (int r = 0; r < 16; ++r) { d[r] = oacc0[r]; d[16 + r] = oacc1[r]; }
    d[32] = lp;
  }
  __syncthreads();
  if (jh == 0) {
    const float* s = cb + (iblk * 64 + lane) * 33;
#pragma unroll
    for (int r = 0; r < 16; ++r) { oacc0[r] += s[r]; oacc1[r] += s[16 + r]; }
    lp += s[32];
    const float inv = 1.f / lp;
    const int b = bh >> 2, hh = bh & 3;
    const int n = qtile * 64 + iblk * 32 + l5;
    u16* obase = att + ((size_t)(b * 1024 + n)) * 256 + hh * 64;
#pragma unroll
    for (int g = 0; g < 4; ++g) {
      ushort4 o0, o1;
      o0.x = f2bf(oacc0[4 * g + 0] * inv);
      o0.y = f2bf(oacc0[4 * g + 1] * inv);
      o0.z = f2bf(oacc0[4 * g + 2] * inv);
      o0.w = f2bf(oacc0[4 * g + 3] * inv);
      o1.x = f2bf(oacc1[4 * g + 0] * inv);
      o1.y = f2bf(oacc1[4 * g + 1] * inv);
      o1.z = f2bf(oacc1[4 * g + 2] * inv);
      o1.w = f2bf(oacc1[4 * g + 3] * inv);
      *(ushort4*)(obase + 8 * g + 4 * h) = o0;
      *(ushort4*)(obase + 32 + 8 * g + 4 * h) = o1;
    }
  }
}

// ---------------------------------------------------------------------------
extern "C" void kernel_launch(void* const* d_in, const int* in_sizes, int n_in,
                              void* d_out, int out_size, void* d_ws, size_t ws_size,
                              hipStream_t stream) {
  const float* x      = (const float*)d_in[0];
  const float* gn_w   = (const float*)d_in[1];
  const float* gn_b   = (const float*)d_in[2];
  const float* qkv_w  = (const float*)d_in[3];
  const float* qkv_b  = (const float*)d_in[4];
  const float* proj_w = (const float*)d_in[5];
  const float* proj_b = (const float*)d_in[6];
  float* out = (float*)d_out;

  char* ws = (char*)d_ws;
  float* stats = (float*)(ws + 0);            // 128*2 fp32
  u16* qwb = (u16*)(ws + 4096);               // 768*256 bf16
  u16* pwb = (u16*)(ws + 397312);             // 256*256 bf16
  u16* qsw = (u16*)(ws + 8916992);            // [64bh][16qt][64x64 swz image]
  u16* ksw = (u16*)(ws + 17305600);           // [64bh][16jc][64x64 swz image]
  u16* vsw = (u16*)(ws + 25694208);           // [64bh][16jc][64x64 swz image]
  u16* att = (u16*)(ws + 34082816);           // [16][1024][256] bf16

  prep<<<384, 256, 0, stream>>>(qkv_w, proj_w, x, qwb, pwb, stats);
  gemm_qkv<<<768, 256, 0, stream>>>(qwb, x, stats, gn_w, gn_b, qkv_b,
                                    qsw, ksw, vsw);
  attn_fused<<<1024, 256, 0, stream>>>(qsw, ksw, vsw, att);
  gemm_proj<<<dim3(128, 4), 256, 0, stream>>>(pwb, att, proj_b, x, out);
}